// Round 10
// baseline (662.230 us; speedup 1.0000x reference)
//
#include <hip/hip_runtime.h>
#include <hip/hip_fp16.h>
#include <math.h>

typedef unsigned int uint;
typedef unsigned short ushort;

#define B_ 256
#define T_ 512
#define F_ 378
#define C_ 128
#define H_ 64
#define KPAD 1152   // 3 * 384

using f32x4 = __attribute__((ext_vector_type(4))) float;
using bf16x8 = __attribute__((ext_vector_type(8))) short;
using f16x8 = __attribute__((ext_vector_type(8))) _Float16;
using fp16x2r = __attribute__((ext_vector_type(2))) __fp16;  // cvt_pkrtz ret

__device__ __forceinline__ ushort f2bf(float f) {
  union { float f; uint u; } c; c.f = f;
  uint r = (c.u + 0x7fffu + ((c.u >> 16) & 1u)) >> 16;
  return (ushort)r;
}
__device__ __forceinline__ uint packbf2(float a, float b) {
  return (uint)f2bf(a) | (((uint)f2bf(b)) << 16);
}
__device__ __forceinline__ ushort f2h(float f) {
  __half h = __float2half(f);
  return *(ushort*)&h;
}
__device__ __forceinline__ float h2f(ushort u) {
  __half h;
  *(ushort*)&h = u;
  return __half2float(h);
}
// pre-scaled activations: inputs already multiplied by -1.4427 (sigm) or
// +2.8854 (tanh) at weight-pack time; v_exp_f32 computes 2^x.
__device__ __forceinline__ float sigm_pre(float v) {
  return __builtin_amdgcn_rcpf(1.f + __builtin_amdgcn_exp2f(v));
}
__device__ __forceinline__ float tanh_pre(float v) {
  return fmaf(-2.f, __builtin_amdgcn_rcpf(1.f + __builtin_amdgcn_exp2f(v)), 1.f);
}
__device__ __forceinline__ float tanh_fast(float v) {  // unscaled input
  return fmaf(-2.f,
              __builtin_amdgcn_rcpf(1.f + __builtin_amdgcn_exp2f(2.885390082f * v)),
              1.f);
}
#define SC_SIG -1.442695041f
#define SC_TANH 2.885390082f

// ---------------- pack conv w -> wbT[c][kk], kk = k*384+f, bf16 ------------
__global__ __launch_bounds__(256) void pack_w_kernel(
    const float* __restrict__ w, ushort* __restrict__ wbT) {
  int i = blockIdx.x * 256 + threadIdx.x;
  if (i >= C_ * KPAD) return;
  int c = i / KPAD, kk = i - c * KPAD;
  int k = kk / 384, f = kk - k * 384;
  float v = (f < F_) ? w[c * (F_ * 3) + f * 3 + k] : 0.f;
  wbT[i] = f2bf(v);
}

// ---- pack w_ih -> wP[dir][g''][128] bf16, PRE-SCALED ----------------------
// g'' = wv*128 + q*32 + j*4 + e  ->  orig gate row e*64 + (32wv + 8q + j).
// scale: gates i,f,o by -1.4427 (sigm), gate g by +2.8854 (tanh).
__global__ __launch_bounds__(256) void pack_wiP_kernel(
    const float* __restrict__ wf, const float* __restrict__ wb,
    ushort* __restrict__ wP) {
  int i = blockIdx.x * 256 + threadIdx.x;  // 2*256*128 = 65536
  int dir = i >> 15, rem = i & 32767;
  int gp = rem >> 7, k = rem & 127;
  int wv = gp >> 7, rr = gp & 127;
  int q = rr >> 5, j = (rr >> 2) & 7, e = rr & 3;
  int u = 32 * wv + 8 * q + j;
  const float* src = dir ? wb : wf;
  float scale = (e == 2) ? SC_TANH : SC_SIG;
  wP[i] = f2bf(src[(e * 64 + u) * 128 + k] * scale);
}

// ---- pack w_hh -> whhP[dir][rP][64] FP16, PRE-SCALED ----------------------
// rP = wv*128 + n*16 + irow; n = e*2+nn; irow=(4q'+r) ->
// orig row = e*64 + (32wv + 8*(irow>>2) + 4nn + (irow&3)).
__global__ __launch_bounds__(256) void pack_whhP_kernel(
    const float* __restrict__ wf, const float* __restrict__ wb,
    ushort* __restrict__ whhP) {
  int i = blockIdx.x * 256 + threadIdx.x;  // 2*256*64 = 32768
  if (i >= 32768) return;
  int dir = i >> 14, rem = i & 16383;
  int rP = rem >> 6, k = rem & 63;
  int wv = rP >> 7, rr = rP & 127;
  int n = rr >> 4, irow = rr & 15;
  int e = n >> 1, nn = n & 1;
  int u = 32 * wv + 8 * (irow >> 2) + 4 * nn + (irow & 3);
  const float* src = dir ? wb : wf;
  float scale = (e == 2) ? SC_TANH : SC_SIG;
  whhP[i] = f2h(src[(e * 64 + u) * 64 + k] * scale);
}

// ---- pack bias -> biasP[dir][g''] fp32, same order+scale as wP ------------
__global__ __launch_bounds__(256) void pack_biasP_kernel(
    const float* __restrict__ bf, const float* __restrict__ bb,
    float* __restrict__ biasP) {
  int i = blockIdx.x * 256 + threadIdx.x;  // 512
  if (i >= 512) return;
  int dir = i >> 8, gp = i & 255;
  int wv = gp >> 7, rr = gp & 127;
  int q = rr >> 5, j = (rr >> 2) & 7, e = rr & 3;
  int u = 32 * wv + 8 * q + j;
  const float* src = dir ? bb : bf;
  float scale = (e == 2) ? SC_TANH : SC_SIG;
  biasP[i] = src[e * 64 + u] * scale;
}

// ---------------- Conv1d as implicit GEMM, bf16 MFMA (unchanged) -----------
__global__ __launch_bounds__(256, 2) void conv_gemm_kernel(
    const float* __restrict__ x, const ushort* __restrict__ wbT,
    const float* __restrict__ bias, ushort* __restrict__ y) {
  __shared__ __align__(16) char xsb[130 * 128];
  __shared__ __align__(16) char bsb[128 * 384];
  const int tid = threadIdx.x;
  const int lane = tid & 63;
  const int wr = (tid >> 7) & 1;
  const int wc = (tid >> 6) & 1;
  const int b = blockIdx.x >> 2;
  const int t0 = (blockIdx.x & 3) << 7;

  f32x4 acc[4][4];
#pragma unroll
  for (int m = 0; m < 4; ++m)
#pragma unroll
    for (int n = 0; n < 4; ++n) acc[m][n] = (f32x4)(0.f);

  for (int fs = 0; fs < 6; ++fs) {
    __syncthreads();
    {
      auto stage_a = [&](int r, int h) {
        const int t = t0 - 1 + r;
        const bool ok = (t >= 0) && (t < T_);
        const float* srow = x + ((long)b * T_ + (ok ? t : 0)) * F_;
        const int fb = fs * 64 + h * 32;
        char* dst = xsb + r * 128;
        const int sw = (r & 7) << 4;
        uint pk[16];
        if (ok && fb + 31 < F_) {
#pragma unroll
          for (int j = 0; j < 16; ++j) {
            float2 v = *(const float2*)(srow + fb + 2 * j);
            pk[j] = packbf2(v.x, v.y);
          }
        } else {
#pragma unroll
          for (int j = 0; j < 16; ++j) {
            const int f = fb + 2 * j;
            float a = (ok && f < F_) ? srow[f] : 0.f;
            float c2 = (ok && f + 1 < F_) ? srow[f + 1] : 0.f;
            pk[j] = packbf2(a, c2);
          }
        }
#pragma unroll
        for (int j = 0; j < 4; ++j) {
          uint4 p = {pk[4 * j], pk[4 * j + 1], pk[4 * j + 2], pk[4 * j + 3]};
          *(uint4*)(dst + ((h * 64 + j * 16) ^ sw)) = p;
        }
      };
      stage_a(tid >> 1, tid & 1);
      if (tid < 4) stage_a(128 + (tid >> 1), tid & 1);
    }
    {
      const int c = tid >> 1, h = tid & 1;
      const ushort* src = wbT + c * KPAD + fs * 64 + h * 32;
      char* drow = bsb + c * 384;
      const int sw = (c & 7) << 4;
#pragma unroll
      for (int k = 0; k < 3; ++k)
#pragma unroll
        for (int j = 0; j < 4; ++j) {
          uint4 v = *(const uint4*)(src + k * 384 + j * 8);
          *(uint4*)(drow + k * 128 + ((h * 64 + j * 16) ^ sw)) = v;
        }
    }
    __syncthreads();

#pragma unroll
    for (int k = 0; k < 3; ++k) {
#pragma unroll
      for (int s = 0; s < 2; ++s) {
        bf16x8 af[4], bfx[4];
        const int ksub = s * 64 + ((lane >> 4) << 4);
#pragma unroll
        for (int m = 0; m < 4; ++m) {
          const int rr = wr * 64 + m * 16 + (lane & 15) + k;
          af[m] = *(const bf16x8*)(xsb + rr * 128 + (ksub ^ ((rr & 7) << 4)));
        }
#pragma unroll
        for (int n = 0; n < 4; ++n) {
          const int c = wc * 64 + n * 16 + (lane & 15);
          bfx[n] =
              *(const bf16x8*)(bsb + c * 384 + k * 128 + (ksub ^ ((c & 7) << 4)));
        }
#pragma unroll
        for (int m = 0; m < 4; ++m)
#pragma unroll
          for (int n = 0; n < 4; ++n)
            acc[m][n] = __builtin_amdgcn_mfma_f32_16x16x32_bf16(
                af[m], bfx[n], acc[m][n], 0, 0, 0);
      }
    }
  }

  __syncthreads();
  float bc[4];
#pragma unroll
  for (int n = 0; n < 4; ++n) bc[n] = bias[wc * 64 + n * 16 + (lane & 15)];
#pragma unroll
  for (int m = 0; m < 4; ++m) {
#pragma unroll
    for (int n = 0; n < 4; ++n) {
      const int col = wc * 64 + n * 16 + (lane & 15);
#pragma unroll
      for (int r = 0; r < 4; ++r) {
        const int row = wr * 64 + m * 16 + ((lane >> 4) << 2) + r;
        float v = acc[m][n][r] + bc[n];
        v = v > 0.f ? v : 0.f;
        *(ushort*)(bsb + row * 256 + ((col * 2) ^ ((row & 7) << 4))) = f2bf(v);
      }
    }
  }
  __syncthreads();
  const int w = tid >> 6;
#pragma unroll
  for (int p = 0; p < 8; ++p) {
    const int rowb = p * 16 + w * 4 + (lane >> 4);
    const int colb = (lane & 15) * 16;
    uint4 v = *(const uint4*)(bsb + rowb * 256 + (colb ^ ((rowb & 7) << 4)));
    *(uint4*)((char*)(y + ((long)b * T_ + t0 + rowb) * 128) + colb) = v;
  }
}

// ---------------- xg GEMM: xgP[dir][b*T+t][256] fp16 = y @ wP^T + bias -----
__global__ __launch_bounds__(256, 2) void xg_gemm_kernel(
    const ushort* __restrict__ y, const ushort* __restrict__ wP,
    const float* __restrict__ biasP, ushort* __restrict__ xgP) {
  __shared__ __align__(16) char xsb[128 * 256];
  __shared__ __align__(16) char bsb[128 * 256];
  const int tid = threadIdx.x;
  const int lane = tid & 63;
  const int wr = (tid >> 7) & 1;
  const int wc = (tid >> 6) & 1;
  const int mb = blockIdx.x >> 2;
  const int nb = blockIdx.x & 3;
  const int m0 = mb << 7;
  const int dirBT = (nb >> 1) * (B_ * T_);
  const int gbase = (nb >> 1) * 256 + (nb & 1) * 128;

  {
    const int r = tid >> 1, h = tid & 1;
    const int sw = (r & 7) << 4;
    const ushort* sa = y + ((long)(m0 + r)) * 128 + h * 64;
    const ushort* sb = wP + (gbase + r) * 128 + h * 64;
    char* da = xsb + r * 256;
    char* db = bsb + r * 256;
#pragma unroll
    for (int j = 0; j < 8; ++j) {
      uint4 va = *(const uint4*)(sa + 8 * j);
      uint4 vb = *(const uint4*)(sb + 8 * j);
      const int inner = (h * 128 + j * 16) ^ sw;
      *(uint4*)(da + inner) = va;
      *(uint4*)(db + inner) = vb;
    }
  }
  __syncthreads();

  f32x4 acc[4][4];
#pragma unroll
  for (int m = 0; m < 4; ++m)
#pragma unroll
    for (int n = 0; n < 4; ++n) acc[m][n] = (f32x4)(0.f);

#pragma unroll
  for (int ks = 0; ks < 4; ++ks) {
    bf16x8 af[4], bfx[4];
    const int ksub = ks * 64 + ((lane >> 4) << 4);
#pragma unroll
    for (int m = 0; m < 4; ++m) {
      const int rr = wr * 64 + m * 16 + (lane & 15);
      af[m] = *(const bf16x8*)(xsb + rr * 256 + (ksub ^ ((rr & 7) << 4)));
    }
#pragma unroll
    for (int n = 0; n < 4; ++n) {
      const int c = wc * 64 + n * 16 + (lane & 15);
      bfx[n] = *(const bf16x8*)(bsb + c * 256 + (ksub ^ ((c & 7) << 4)));
    }
#pragma unroll
    for (int m = 0; m < 4; ++m)
#pragma unroll
      for (int n = 0; n < 4; ++n)
        acc[m][n] = __builtin_amdgcn_mfma_f32_16x16x32_bf16(af[m], bfx[n],
                                                            acc[m][n], 0, 0, 0);
  }

  __syncthreads();
  float bc[4];
#pragma unroll
  for (int n = 0; n < 4; ++n)
    bc[n] = biasP[gbase + wc * 64 + n * 16 + (lane & 15)];
#pragma unroll
  for (int m = 0; m < 4; ++m) {
#pragma unroll
    for (int n = 0; n < 4; ++n) {
      const int col = wc * 64 + n * 16 + (lane & 15);
#pragma unroll
      for (int r = 0; r < 4; ++r) {
        const int row = wr * 64 + m * 16 + ((lane >> 4) << 2) + r;
        float v = acc[m][n][r] + bc[n];
        *(ushort*)(bsb + row * 256 + ((col * 2) ^ ((row & 7) << 4))) = f2h(v);
      }
    }
  }
  __syncthreads();
  const int w = tid >> 6;
#pragma unroll
  for (int p = 0; p < 8; ++p) {
    const int rowb = p * 16 + w * 4 + (lane >> 4);
    const int colb = (lane & 15) * 16;
    uint4 v = *(const uint4*)(bsb + rowb * 256 + (colb ^ ((rowb & 7) << 4)));
    *(uint4*)((char*)xgP + ((long)(dirBT + m0 + rowb)) * 512 + (nb & 1) * 256 +
              colb) = v;
  }
}

// ---------------- LSTM scan: 16 seqs/group, TWO waves, self-owned B-frags --
// Wave wv owns units 32wv..32wv+31; lane (s,q) owns units 32wv+8q+{0..7} =
// exactly its own B-frag k-slots (k=8q+j). Per step: write own h (16B,
// linear/conflict-free) -> 8 self-MFMAs (issue before barrier) -> barrier ->
// read other wave's 16B -> 8 accumulate-MFMAs -> nonlinearity (8 units,
// pre-scaled weights) -> pack via cvt_pkrtz. No swizzles, 4 LDS ops/step.
union U2 { uint u; __half2 h2; };
union UH { uint4 u; f16x8 h; };
union UP { fp16x2r h; uint u; };

#define UNIT(J2, IFW, GOW, AI, AF, AG, AO, RR)                                 \
  {                                                                            \
    U2 ua, ub;                                                                 \
    ua.u = (IFW);                                                              \
    ub.u = (GOW);                                                              \
    float2 xif = __half22float2(ua.h2);                                        \
    float2 xgo = __half22float2(ub.h2);                                        \
    float pi = acc[AI][RR] + xif.x, pf = acc[AF][RR] + xif.y;                  \
    float pg = acc[AG][RR] + xgo.x, po = acc[AO][RR] + xgo.y;                  \
    float si = sigm_pre(pi), sf = sigm_pre(pf), so = sigm_pre(po);             \
    float tg = tanh_pre(pg);                                                   \
    cst[J2] = fmaf(sf, cst[J2], si * tg);                                      \
    hv[J2] = so * tanh_fast(cst[J2]);                                          \
  }

#define LSTEP(J, Q0, Q1, Q2, Q3)                                               \
  do {                                                                         \
    const int t_ = t0ph + (J);                                                 \
    const int p_ = (J) & 1;                                                    \
    const uint4 c0 = Q0, c1 = Q1, c2 = Q2, c3 = Q3;                            \
    UH sh;                                                                     \
    sh.u = huv;                                                                \
    *(uint4*)(xch + p_ * 2048 + wv * 1024 + s * 64 + q * 16) = huv;            \
    f32x4 acc[8];                                                              \
    _Pragma("unroll") for (int n = 0; n < 8; ++n) acc[n] =                     \
        __builtin_amdgcn_mfma_f32_16x16x32_f16(afS[n], sh.h, (f32x4)(0.f), 0,  \
                                               0, 0);                          \
    {                                                                          \
      int tp = t_ + 2;                                                         \
      tp = tp > T_ - 1 ? T_ - 1 : tp;                                          \
      const int ttp = dir ? (T_ - 1 - tp) : tp;                                \
      const char* xr = xgbase + (long)ttp * 512;                               \
      Q0 = *(const uint4*)xr;                                                  \
      Q1 = *(const uint4*)(xr + 16);                                           \
      Q2 = *(const uint4*)(xr + 32);                                           \
      Q3 = *(const uint4*)(xr + 48);                                           \
    }                                                                          \
    asm volatile("s_waitcnt lgkmcnt(0)" ::: "memory");                         \
    __builtin_amdgcn_sched_barrier(0);                                         \
    __builtin_amdgcn_s_barrier();                                              \
    __builtin_amdgcn_sched_barrier(0);                                         \
    UH oh;                                                                     \
    oh.u = *(const uint4*)(xch + p_ * 2048 + (1 - wv) * 1024 + s * 64 +        \
                           q * 16);                                            \
    asm volatile("s_waitcnt lgkmcnt(0)" ::: "memory");                         \
    __builtin_amdgcn_sched_barrier(0);                                         \
    _Pragma("unroll") for (int n = 0; n < 8; ++n) acc[n] =                     \
        __builtin_amdgcn_mfma_f32_16x16x32_f16(afO[n], oh.h, acc[n], 0, 0, 0); \
    float hv[8];                                                               \
    UNIT(0, c0.x, c0.y, 0, 2, 4, 6, 0)                                         \
    UNIT(1, c0.z, c0.w, 0, 2, 4, 6, 1)                                         \
    UNIT(2, c1.x, c1.y, 0, 2, 4, 6, 2)                                         \
    UNIT(3, c1.z, c1.w, 0, 2, 4, 6, 3)                                         \
    UNIT(4, c2.x, c2.y, 1, 3, 5, 7, 0)                                         \
    UNIT(5, c2.z, c2.w, 1, 3, 5, 7, 1)                                         \
    UNIT(6, c3.x, c3.y, 1, 3, 5, 7, 2)                                         \
    UNIT(7, c3.z, c3.w, 1, 3, 5, 7, 3)                                         \
    {                                                                          \
      UP p0, p1, p2, p3;                                                       \
      p0.h = __builtin_amdgcn_cvt_pkrtz(hv[0], hv[1]);                         \
      p1.h = __builtin_amdgcn_cvt_pkrtz(hv[2], hv[3]);                         \
      p2.h = __builtin_amdgcn_cvt_pkrtz(hv[4], hv[5]);                         \
      p3.h = __builtin_amdgcn_cvt_pkrtz(hv[6], hv[7]);                         \
      huv.x = p0.u;                                                            \
      huv.y = p1.u;                                                            \
      huv.z = p2.u;                                                            \
      huv.w = p3.u;                                                            \
    }                                                                          \
    {                                                                          \
      const int gt = dir ? (T_ - 1 - t_) : t_;                                 \
      *(uint4*)(hRow + (long)gt * 128) = huv;                                  \
    }                                                                          \
  } while (0)

__global__ __launch_bounds__(128, 1) void lstm_seq_kernel(
    const ushort* __restrict__ whhP, const ushort* __restrict__ xgP,
    ushort* __restrict__ hout) {
  const int dir = blockIdx.x >> 4;
  const int bg = blockIdx.x & 15;
  const int tid = threadIdx.x;  // 0..127
  const int wv = tid >> 6;      // wave 0 or 1
  const int lane = tid & 63;
  const int s = lane & 15;  // sequence
  const int q = lane >> 4;  // quarter

  __shared__ __align__(16) char xch[2 * 2048];  // [parity][wv][s][q][16B]

  // pinned A-frags: rows rP = wv*128 + n*16 + s; self k-chunk = own units.
  f16x8 afS[8], afO[8];
  {
    const ushort* base = whhP + (long)dir * 256 * 64;
#pragma unroll
    for (int n = 0; n < 8; ++n) {
      const ushort* rp = base + (wv * 128 + n * 16 + s) * 64;
      afS[n] = *(const f16x8*)(rp + wv * 32 + q * 8);
      afO[n] = *(const f16x8*)(rp + (1 - wv) * 32 + q * 8);
    }
  }

  const int b = bg * 16 + s;
  const long xgrow = ((long)dir * B_ + b) * T_;
  const char* xgbase = (const char*)xgP + xgrow * 512 + wv * 256 + q * 64;
  ushort* hRow = hout + (long)b * T_ * 128 + dir * 64 + 32 * wv + 8 * q;

  float cst[8] = {0.f, 0.f, 0.f, 0.f, 0.f, 0.f, 0.f, 0.f};
  uint4 huv = {0u, 0u, 0u, 0u};

  // 2-deep xg prefetch (64B/step/lane)
  uint4 A0, A1, A2, A3, B0, B1, B2, B3;
  {
    const char* xr = xgbase + (long)(dir ? T_ - 1 : 0) * 512;
    A0 = *(const uint4*)xr;
    A1 = *(const uint4*)(xr + 16);
    A2 = *(const uint4*)(xr + 32);
    A3 = *(const uint4*)(xr + 48);
  }
  {
    const char* xr = xgbase + (long)(dir ? T_ - 2 : 1) * 512;
    B0 = *(const uint4*)xr;
    B1 = *(const uint4*)(xr + 16);
    B2 = *(const uint4*)(xr + 32);
    B3 = *(const uint4*)(xr + 48);
  }

  for (int ph = 0; ph < 128; ++ph) {
    const int t0ph = ph * 4;
    LSTEP(0, A0, A1, A2, A3);
    LSTEP(1, B0, B1, B2, B3);
    LSTEP(2, A0, A1, A2, A3);
    LSTEP(3, B0, B1, B2, B3);
  }
}

// ---------------- Attention pool + LayerNorm + FC (fp16 hio) ---------------
__global__ __launch_bounds__(256) void head_kernel(
    const ushort* __restrict__ hio, const float* __restrict__ attn_w,
    const float* __restrict__ attn_b, const float* __restrict__ ln_g,
    const float* __restrict__ ln_b, const float* __restrict__ fc_w,
    const float* __restrict__ fc_b, float* __restrict__ res) {
  const int b = blockIdx.x;
  const int tid = threadIdx.x;
  __shared__ __align__(16) float aw[128];
  __shared__ float l[T_];
  __shared__ float red[16];
  __shared__ float pp[2][128];
  __shared__ float normed[128];
  if (tid < 128) aw[tid] = attn_w[tid];
  __syncthreads();
  const float ab = attn_b[0];

  for (int t = tid; t < T_; t += 256) {
    const ushort* row = hio + ((long)b * T_ + t) * 128;
    float a = ab;
#pragma unroll
    for (int d = 0; d < 128; d += 8) {
      uint4 v = *(const uint4*)(row + d);
      float2 p0 = __half22float2(*(const __half2*)&v.x);
      float2 p1 = __half22float2(*(const __half2*)&v.y);
      float2 p2 = __half22float2(*(const __half2*)&v.z);
      float2 p3 = __half22float2(*(const __half2*)&v.w);
      a += p0.x * aw[d] + p0.y * aw[d + 1] + p1.x * aw[d + 2] +
           p1.y * aw[d + 3] + p2.x * aw[d + 4] + p2.y * aw[d + 5] +
           p3.x * aw[d + 6] + p3.y * aw[d + 7];
    }
    l[t] = a;
  }
  __syncthreads();

  float v0 = l[tid], v1 = l[tid + 256];
  float m = fmaxf(v0, v1);
#pragma unroll
  for (int off = 32; off >= 1; off >>= 1) m = fmaxf(m, __shfl_xor(m, off));
  if ((tid & 63) == 0) red[tid >> 6] = m;
  __syncthreads();
  m = fmaxf(fmaxf(red[0], red[1]), fmaxf(red[2], red[3]));
  float e0 = __expf(v0 - m), e1 = __expf(v1 - m);
  float ssum = e0 + e1;
#pragma unroll
  for (int off = 32; off >= 1; off >>= 1) ssum += __shfl_xor(ssum, off);
  if ((tid & 63) == 0) red[4 + (tid >> 6)] = ssum;
  __syncthreads();
  float inv = 1.f / (red[4] + red[5] + red[6] + red[7]);
  l[tid] = e0 * inv;
  l[tid + 256] = e1 * inv;
  __syncthreads();

  const int d = tid & 127, half = tid >> 7;
  float p = 0.f;
  for (int t = half * 256; t < half * 256 + 256; ++t)
    p += l[t] * h2f(hio[((long)b * T_ + t) * 128 + d]);
  pp[half][d] = p;
  __syncthreads();

  if (tid < 128) {
    float pv = pp[0][tid] + pp[1][tid];
    float s1 = pv, s2 = pv * pv;
#pragma unroll
    for (int off = 32; off >= 1; off >>= 1) {
      s1 += __shfl_xor(s1, off);
      s2 += __shfl_xor(s2, off);
    }
    if ((tid & 63) == 0) {
      red[8 + (tid >> 6) * 2] = s1;
      red[9 + (tid >> 6) * 2] = s2;
    }
  }
  __syncthreads();
  if (tid < 128) {
    float s1 = red[8] + red[10], s2 = red[9] + red[11];
    float mu = s1 * (1.f / 128.f);
    float var = s2 * (1.f / 128.f) - mu * mu;
    float rinv = rsqrtf(var + 1e-5f);
    float pv = pp[0][tid] + pp[1][tid];
    normed[tid] = (pv - mu) * rinv * ln_g[tid] + ln_b[tid];
  }
  __syncthreads();

  if (tid < 2) {
    float a = fc_b[tid];
    for (int d2 = 0; d2 < 128; ++d2) a += normed[d2] * fc_w[tid * 128 + d2];
    res[b * 2 + tid] = a;
  }
}

extern "C" void kernel_launch(void* const* d_in, const int* in_sizes, int n_in,
                              void* d_out, int out_size, void* d_ws,
                              size_t ws_size, hipStream_t stream) {
  const float* x = (const float*)d_in[0];
  const float* conv_w = (const float*)d_in[1];
  const float* conv_b = (const float*)d_in[2];
  const float* w_ih_f = (const float*)d_in[3];
  const float* w_hh_f = (const float*)d_in[4];
  const float* b_f = (const float*)d_in[5];
  const float* w_ih_b = (const float*)d_in[6];
  const float* w_hh_b = (const float*)d_in[7];
  const float* b_b = (const float*)d_in[8];
  const float* attn_w = (const float*)d_in[9];
  const float* attn_b = (const float*)d_in[10];
  const float* ln_g = (const float*)d_in[11];
  const float* ln_b = (const float*)d_in[12];
  const float* fc_w = (const float*)d_in[13];
  const float* fc_b = (const float*)d_in[14];
  float* res = (float*)d_out;

  // ws layout (~161 MiB):
  char* ws = (char*)d_ws;
  ushort* wbT = (ushort*)ws;                      // 294,912 B
  ushort* wP = (ushort*)(ws + 0x60000);           // 131,072 B (scaled)
  ushort* whhP = (ushort*)(ws + 0x80000);         // 65,536 B (fp16, scaled)
  float* biasP = (float*)(ws + 0x90000);          // 2,048 B (scaled)
  ushort* xgP = (ushort*)(ws + 0x100000);         // 134,217,728 B (fp16)
  ushort* y = (ushort*)(ws + 0x100000 + 134217728);  // 33,554,432 B
  ushort* hout = y;  // aliases y (fp16): y is dead after xg_gemm

  pack_w_kernel<<<576, 256, 0, stream>>>(conv_w, wbT);
  pack_wiP_kernel<<<256, 256, 0, stream>>>(w_ih_f, w_ih_b, wP);
  pack_whhP_kernel<<<128, 256, 0, stream>>>(w_hh_f, w_hh_b, whhP);
  pack_biasP_kernel<<<2, 256, 0, stream>>>(b_f, b_b, biasP);
  conv_gemm_kernel<<<B_ * (T_ / 128), 256, 0, stream>>>(x, wbT, conv_b, y);
  xg_gemm_kernel<<<(B_ * T_ / 128) * 4, 256, 0, stream>>>(y, wP, biasP, xgP);
  lstm_seq_kernel<<<32, 128, 0, stream>>>(whhP, xgP, hout);
  head_kernel<<<B_, 256, 0, stream>>>(hout, attn_w, attn_b, ln_g, ln_b, fc_w,
                                      fc_b, res);
}

// Round 11
// 600.815 us; speedup vs baseline: 1.1022x; 1.1022x over previous
//
#include <hip/hip_runtime.h>
#include <hip/hip_fp16.h>
#include <math.h>

typedef unsigned int uint;
typedef unsigned short ushort;

#define B_ 256
#define T_ 512
#define F_ 378
#define C_ 128
#define H_ 64
#define KPAD 1152   // 3 * 384

using f32x4 = __attribute__((ext_vector_type(4))) float;
using bf16x8 = __attribute__((ext_vector_type(8))) short;
using f16x8 = __attribute__((ext_vector_type(8))) _Float16;

__device__ __forceinline__ ushort f2bf(float f) {
  union { float f; uint u; } c; c.f = f;
  uint r = (c.u + 0x7fffu + ((c.u >> 16) & 1u)) >> 16;
  return (ushort)r;
}
__device__ __forceinline__ uint packbf2(float a, float b) {
  return (uint)f2bf(a) | (((uint)f2bf(b)) << 16);
}
__device__ __forceinline__ ushort f2h(float f) {
  __half h = __float2half(f);
  return *(ushort*)&h;
}
__device__ __forceinline__ float h2f(ushort u) {
  __half h;
  *(ushort*)&h = u;
  return __half2float(h);
}
// pre-scaled activations: inputs already multiplied by -1.4427 (sigm) or
// +2.8854 (tanh) at weight-pack time; v_exp_f32 computes 2^x.
__device__ __forceinline__ float sigm_pre(float v) {
  return __builtin_amdgcn_rcpf(1.f + __builtin_amdgcn_exp2f(v));
}
__device__ __forceinline__ float tanh_pre(float v) {
  return fmaf(-2.f, __builtin_amdgcn_rcpf(1.f + __builtin_amdgcn_exp2f(v)), 1.f);
}
__device__ __forceinline__ float tanh_fast(float v) {  // unscaled input
  return fmaf(-2.f,
              __builtin_amdgcn_rcpf(1.f + __builtin_amdgcn_exp2f(2.885390082f * v)),
              1.f);
}
#define SC_SIG -1.442695041f
#define SC_TANH 2.885390082f

// ---------------- pack conv w -> wbT[c][kk], kk = k*384+f, bf16 ------------
__global__ __launch_bounds__(256) void pack_w_kernel(
    const float* __restrict__ w, ushort* __restrict__ wbT) {
  int i = blockIdx.x * 256 + threadIdx.x;
  if (i >= C_ * KPAD) return;
  int c = i / KPAD, kk = i - c * KPAD;
  int k = kk / 384, f = kk - k * 384;
  float v = (f < F_) ? w[c * (F_ * 3) + f * 3 + k] : 0.f;
  wbT[i] = f2bf(v);
}

// ---- pack w_ih -> wP[dir][g''][128] bf16, PRE-SCALED (4-wave mapping) -----
// g'' = w*64 + q*16 + n*4 + e -> orig gate row e*64 + (16w + 4q + n).
__global__ __launch_bounds__(256) void pack_wiP_kernel(
    const float* __restrict__ wf, const float* __restrict__ wb,
    ushort* __restrict__ wP) {
  int i = blockIdx.x * 256 + threadIdx.x;  // 2*256*128 = 65536
  int dir = i >> 15, rem = i & 32767;
  int gp = rem >> 7, k = rem & 127;
  int e = gp & 3, n = (gp >> 2) & 3, q = (gp >> 4) & 3, w = gp >> 6;
  int u = 16 * w + 4 * q + n;
  const float* src = dir ? wb : wf;
  float scale = (e == 2) ? SC_TANH : SC_SIG;
  wP[i] = f2bf(src[(e * 64 + u) * 128 + k] * scale);
}

// ---- pack w_hh -> whhP[dir][r][64] FP16, PRE-SCALED (4-wave mapping) ------
// r = 64w + 16n + 4q + e -> gate e of unit 16w + 4q + n.
__global__ __launch_bounds__(256) void pack_whhP_kernel(
    const float* __restrict__ wf, const float* __restrict__ wb,
    ushort* __restrict__ whhP) {
  int i = blockIdx.x * 256 + threadIdx.x;  // 2*256*64 = 32768
  if (i >= 32768) return;
  int dir = i >> 14, rem = i & 16383;
  int r = rem >> 6, k = rem & 63;
  int e = r & 3, q = (r >> 2) & 3, n = (r >> 4) & 3, w = r >> 6;
  int u = 16 * w + 4 * q + n;
  const float* src = dir ? wb : wf;
  float scale = (e == 2) ? SC_TANH : SC_SIG;
  whhP[i] = f2h(src[(e * 64 + u) * 64 + k] * scale);
}

// ---- pack bias -> biasP[dir][g''] fp32, same order+scale as wP ------------
__global__ __launch_bounds__(256) void pack_biasP_kernel(
    const float* __restrict__ bf, const float* __restrict__ bb,
    float* __restrict__ biasP) {
  int i = blockIdx.x * 256 + threadIdx.x;  // 512
  if (i >= 512) return;
  int dir = i >> 8, gp = i & 255;
  int e = gp & 3, n = (gp >> 2) & 3, q = (gp >> 4) & 3, w = gp >> 6;
  int u = 16 * w + 4 * q + n;
  const float* src = dir ? bb : bf;
  float scale = (e == 2) ? SC_TANH : SC_SIG;
  biasP[i] = src[e * 64 + u] * scale;
}

// ---------------- Conv1d as implicit GEMM, bf16 MFMA (unchanged) -----------
__global__ __launch_bounds__(256, 2) void conv_gemm_kernel(
    const float* __restrict__ x, const ushort* __restrict__ wbT,
    const float* __restrict__ bias, ushort* __restrict__ y) {
  __shared__ __align__(16) char xsb[130 * 128];
  __shared__ __align__(16) char bsb[128 * 384];
  const int tid = threadIdx.x;
  const int lane = tid & 63;
  const int wr = (tid >> 7) & 1;
  const int wc = (tid >> 6) & 1;
  const int b = blockIdx.x >> 2;
  const int t0 = (blockIdx.x & 3) << 7;

  f32x4 acc[4][4];
#pragma unroll
  for (int m = 0; m < 4; ++m)
#pragma unroll
    for (int n = 0; n < 4; ++n) acc[m][n] = (f32x4)(0.f);

  for (int fs = 0; fs < 6; ++fs) {
    __syncthreads();
    {
      auto stage_a = [&](int r, int h) {
        const int t = t0 - 1 + r;
        const bool ok = (t >= 0) && (t < T_);
        const float* srow = x + ((long)b * T_ + (ok ? t : 0)) * F_;
        const int fb = fs * 64 + h * 32;
        char* dst = xsb + r * 128;
        const int sw = (r & 7) << 4;
        uint pk[16];
        if (ok && fb + 31 < F_) {
#pragma unroll
          for (int j = 0; j < 16; ++j) {
            float2 v = *(const float2*)(srow + fb + 2 * j);
            pk[j] = packbf2(v.x, v.y);
          }
        } else {
#pragma unroll
          for (int j = 0; j < 16; ++j) {
            const int f = fb + 2 * j;
            float a = (ok && f < F_) ? srow[f] : 0.f;
            float c2 = (ok && f + 1 < F_) ? srow[f + 1] : 0.f;
            pk[j] = packbf2(a, c2);
          }
        }
#pragma unroll
        for (int j = 0; j < 4; ++j) {
          uint4 p = {pk[4 * j], pk[4 * j + 1], pk[4 * j + 2], pk[4 * j + 3]};
          *(uint4*)(dst + ((h * 64 + j * 16) ^ sw)) = p;
        }
      };
      stage_a(tid >> 1, tid & 1);
      if (tid < 4) stage_a(128 + (tid >> 1), tid & 1);
    }
    {
      const int c = tid >> 1, h = tid & 1;
      const ushort* src = wbT + c * KPAD + fs * 64 + h * 32;
      char* drow = bsb + c * 384;
      const int sw = (c & 7) << 4;
#pragma unroll
      for (int k = 0; k < 3; ++k)
#pragma unroll
        for (int j = 0; j < 4; ++j) {
          uint4 v = *(const uint4*)(src + k * 384 + j * 8);
          *(uint4*)(drow + k * 128 + ((h * 64 + j * 16) ^ sw)) = v;
        }
    }
    __syncthreads();

#pragma unroll
    for (int k = 0; k < 3; ++k) {
#pragma unroll
      for (int s = 0; s < 2; ++s) {
        bf16x8 af[4], bfx[4];
        const int ksub = s * 64 + ((lane >> 4) << 4);
#pragma unroll
        for (int m = 0; m < 4; ++m) {
          const int rr = wr * 64 + m * 16 + (lane & 15) + k;
          af[m] = *(const bf16x8*)(xsb + rr * 128 + (ksub ^ ((rr & 7) << 4)));
        }
#pragma unroll
        for (int n = 0; n < 4; ++n) {
          const int c = wc * 64 + n * 16 + (lane & 15);
          bfx[n] =
              *(const bf16x8*)(bsb + c * 384 + k * 128 + (ksub ^ ((c & 7) << 4)));
        }
#pragma unroll
        for (int m = 0; m < 4; ++m)
#pragma unroll
          for (int n = 0; n < 4; ++n)
            acc[m][n] = __builtin_amdgcn_mfma_f32_16x16x32_bf16(
                af[m], bfx[n], acc[m][n], 0, 0, 0);
      }
    }
  }

  __syncthreads();
  float bc[4];
#pragma unroll
  for (int n = 0; n < 4; ++n) bc[n] = bias[wc * 64 + n * 16 + (lane & 15)];
#pragma unroll
  for (int m = 0; m < 4; ++m) {
#pragma unroll
    for (int n = 0; n < 4; ++n) {
      const int col = wc * 64 + n * 16 + (lane & 15);
#pragma unroll
      for (int r = 0; r < 4; ++r) {
        const int row = wr * 64 + m * 16 + ((lane >> 4) << 2) + r;
        float v = acc[m][n][r] + bc[n];
        v = v > 0.f ? v : 0.f;
        *(ushort*)(bsb + row * 256 + ((col * 2) ^ ((row & 7) << 4))) = f2bf(v);
      }
    }
  }
  __syncthreads();
  const int w = tid >> 6;
#pragma unroll
  for (int p = 0; p < 8; ++p) {
    const int rowb = p * 16 + w * 4 + (lane >> 4);
    const int colb = (lane & 15) * 16;
    uint4 v = *(const uint4*)(bsb + rowb * 256 + (colb ^ ((rowb & 7) << 4)));
    *(uint4*)((char*)(y + ((long)b * T_ + t0 + rowb) * 128) + colb) = v;
  }
}

// ---------------- xg GEMM: xgP[dir][b*T+t][256] fp16 = y @ wP^T + bias -----
__global__ __launch_bounds__(256, 2) void xg_gemm_kernel(
    const ushort* __restrict__ y, const ushort* __restrict__ wP,
    const float* __restrict__ biasP, ushort* __restrict__ xgP) {
  __shared__ __align__(16) char xsb[128 * 256];
  __shared__ __align__(16) char bsb[128 * 256];
  const int tid = threadIdx.x;
  const int lane = tid & 63;
  const int wr = (tid >> 7) & 1;
  const int wc = (tid >> 6) & 1;
  const int mb = blockIdx.x >> 2;
  const int nb = blockIdx.x & 3;
  const int m0 = mb << 7;
  const int dirBT = (nb >> 1) * (B_ * T_);
  const int gbase = (nb >> 1) * 256 + (nb & 1) * 128;

  {
    const int r = tid >> 1, h = tid & 1;
    const int sw = (r & 7) << 4;
    const ushort* sa = y + ((long)(m0 + r)) * 128 + h * 64;
    const ushort* sb = wP + (gbase + r) * 128 + h * 64;
    char* da = xsb + r * 256;
    char* db = bsb + r * 256;
#pragma unroll
    for (int j = 0; j < 8; ++j) {
      uint4 va = *(const uint4*)(sa + 8 * j);
      uint4 vb = *(const uint4*)(sb + 8 * j);
      const int inner = (h * 128 + j * 16) ^ sw;
      *(uint4*)(da + inner) = va;
      *(uint4*)(db + inner) = vb;
    }
  }
  __syncthreads();

  f32x4 acc[4][4];
#pragma unroll
  for (int m = 0; m < 4; ++m)
#pragma unroll
    for (int n = 0; n < 4; ++n) acc[m][n] = (f32x4)(0.f);

#pragma unroll
  for (int ks = 0; ks < 4; ++ks) {
    bf16x8 af[4], bfx[4];
    const int ksub = ks * 64 + ((lane >> 4) << 4);
#pragma unroll
    for (int m = 0; m < 4; ++m) {
      const int rr = wr * 64 + m * 16 + (lane & 15);
      af[m] = *(const bf16x8*)(xsb + rr * 256 + (ksub ^ ((rr & 7) << 4)));
    }
#pragma unroll
    for (int n = 0; n < 4; ++n) {
      const int c = wc * 64 + n * 16 + (lane & 15);
      bfx[n] = *(const bf16x8*)(bsb + c * 256 + (ksub ^ ((c & 7) << 4)));
    }
#pragma unroll
    for (int m = 0; m < 4; ++m)
#pragma unroll
      for (int n = 0; n < 4; ++n)
        acc[m][n] = __builtin_amdgcn_mfma_f32_16x16x32_bf16(af[m], bfx[n],
                                                            acc[m][n], 0, 0, 0);
  }

  __syncthreads();
  float bc[4];
#pragma unroll
  for (int n = 0; n < 4; ++n)
    bc[n] = biasP[gbase + wc * 64 + n * 16 + (lane & 15)];
#pragma unroll
  for (int m = 0; m < 4; ++m) {
#pragma unroll
    for (int n = 0; n < 4; ++n) {
      const int col = wc * 64 + n * 16 + (lane & 15);
#pragma unroll
      for (int r = 0; r < 4; ++r) {
        const int row = wr * 64 + m * 16 + ((lane >> 4) << 2) + r;
        float v = acc[m][n][r] + bc[n];
        *(ushort*)(bsb + row * 256 + ((col * 2) ^ ((row & 7) << 4))) = f2h(v);
      }
    }
  }
  __syncthreads();
  const int w = tid >> 6;
#pragma unroll
  for (int p = 0; p < 8; ++p) {
    const int rowb = p * 16 + w * 4 + (lane >> 4);
    const int colb = (lane & 15) * 16;
    uint4 v = *(const uint4*)(bsb + rowb * 256 + (colb ^ ((rowb & 7) << 4)));
    *(uint4*)((char*)xgP + ((long)(dirBT + m0 + rowb)) * 512 + (nb & 1) * 256 +
              colb) = v;
  }
}

// ---------------- LSTM scan: 4 waves, fp16 MFMA, DUAL-GROUP pipelined ------
// 16 blocks (dir x 8 pairs), 256 threads. Each block runs TWO independent
// 16-seq groups (same dir -> shared w_hh A-frags). Per pair-step: group 0's
// {ds_read -> 8 MFMA -> nonlin} chain overlaps with group 1's issue stream;
// ONE lgkmcnt(0)+barrier per pair. Latency paid once per pair instead of
// once per step (R8 measured ~700cy of serialized latency per step).
union U2 { uint u; __half2 h2; };

#define GSTEP(J, XA, XB, CST, HUV, HBASE, XGB, HROW)                           \
  do {                                                                         \
    const uint4 curA = XA[(J)], curB = XB[(J)];                                \
    {                                                                          \
      int tp = t_ + 4;                                                         \
      tp = tp > T_ - 1 ? T_ - 1 : tp;                                          \
      const int ttp = dir ? (T_ - 1 - tp) : tp;                                \
      const char* xr = (XGB) + (long)ttp * 512;                                \
      XA[(J)] = *(const uint4*)xr;                                             \
      XB[(J)] = *(const uint4*)(xr + 16);                                      \
    }                                                                          \
    f16x8 bh0, bh1;                                                            \
    {                                                                          \
      const char* hb = (HBASE) + p_ * 2048;                                    \
      bh0 = *(const f16x8*)(hb + a0b);                                         \
      bh1 = *(const f16x8*)(hb + a1b);                                         \
    }                                                                          \
    ushort hu[4];                                                              \
    _Pragma("unroll") for (int n = 0; n < 4; ++n) {                            \
      f32x4 ac0 = __builtin_amdgcn_mfma_f32_16x16x32_f16(afA[n], bh0,          \
                                                         (f32x4)(0.f), 0, 0,   \
                                                         0);                   \
      f32x4 ac1 =                                                              \
          __builtin_amdgcn_mfma_f32_16x16x32_f16(afB[n], bh1, ac0, 0, 0, 0);   \
      const uint lo32 = (n & 1) ? ((n & 2) ? curB.z : curA.z)                  \
                                : ((n & 2) ? curB.x : curA.x);                 \
      const uint hi32 = (n & 1) ? ((n & 2) ? curB.w : curA.w)                  \
                                : ((n & 2) ? curB.y : curA.y);                 \
      U2 ua, ub;                                                               \
      ua.u = lo32;                                                             \
      ub.u = hi32;                                                             \
      float2 xif = __half22float2(ua.h2);                                      \
      float2 xgo = __half22float2(ub.h2);                                      \
      float pi = ac1[0] + xif.x, pf = ac1[1] + xif.y;                          \
      float pg = ac1[2] + xgo.x, po = ac1[3] + xgo.y;                          \
      float si = sigm_pre(pi), sf = sigm_pre(pf), so = sigm_pre(po);           \
      float tg = tanh_pre(pg);                                                 \
      CST[n] = fmaf(sf, CST[n], si * tg);                                      \
      hu[n] = f2h(so * tanh_fast(CST[n]));                                     \
    }                                                                          \
    HUV.x = (uint)hu[0] | ((uint)hu[1] << 16);                                 \
    HUV.y = (uint)hu[2] | ((uint)hu[3] << 16);                                 \
    *(uint2*)((HBASE) + (1 - p_) * 2048 + wbb) = HUV;                          \
    *(uint2*)((HROW) + (long)gt_ * 128) = HUV;                                 \
  } while (0)

#define PSTEP(J)                                                               \
  do {                                                                         \
    const int t_ = t0ph + (J);                                                 \
    const int p_ = t_ & 1;                                                     \
    const int gt_ = dir ? (T_ - 1 - t_) : t_;                                  \
    GSTEP(J, x0A, x0B, cst0, huv0, xch, xgb0, hRow0);                          \
    GSTEP(J, x1A, x1B, cst1, huv1, xch + 4096, xgb1, hRow1);                   \
    asm volatile("s_waitcnt lgkmcnt(0)" ::: "memory");                         \
    __builtin_amdgcn_sched_barrier(0);                                         \
    __builtin_amdgcn_s_barrier();                                              \
    __builtin_amdgcn_sched_barrier(0);                                         \
  } while (0)

__global__ __launch_bounds__(256, 1) void lstm_seq_kernel(
    const ushort* __restrict__ whhP, const ushort* __restrict__ xgP,
    ushort* __restrict__ hout) {
  const int dir = blockIdx.x >> 3;
  const int pr = blockIdx.x & 7;
  const int bgA = pr * 2, bgB = pr * 2 + 1;
  const int tid = threadIdx.x;
  const int lane = tid & 63;
  const int w = tid >> 6;   // wave 0..3
  const int s = lane & 15;  // sequence within group
  const int q = lane >> 4;  // quarter

  // [group][parity][16s][64u] fp16 = 2*2*2KB
  __shared__ __align__(16) char xch[8192];
  for (int i = tid; i < 2048; i += 256) ((uint*)xch)[i] = 0u;

  // pinned A-frags (fp16, shared by both groups): rows 64w+16n+s
  f16x8 afA[4], afB[4];
  {
    const ushort* base = whhP + (long)dir * 256 * 64;
#pragma unroll
    for (int n = 0; n < 4; ++n) {
      const ushort* rp = base + (64 * w + 16 * n + s) * 64 + q * 8;
      afA[n] = *(const f16x8*)rp;
      afB[n] = *(const f16x8*)(rp + 32);
    }
  }

  const int hsw = (s & 7) << 4;
  const int a0b = s * 128 + ((q * 16) ^ hsw);          // B-frag k in [0,32)
  const int a1b = s * 128 + ((64 + q * 16) ^ hsw);     // B-frag k in [32,64)
  const int wbb = s * 128 + ((32 * w + 8 * q) ^ hsw);  // b64 h write (4 units)

  const int b0 = bgA * 16 + s, b1 = bgB * 16 + s;
  const int cOff = w * 128 + q * 32;
  const char* xgb0 =
      (const char*)xgP + (((long)dir * B_ + b0) * T_) * 512 + cOff;
  const char* xgb1 =
      (const char*)xgP + (((long)dir * B_ + b1) * T_) * 512 + cOff;
  ushort* hRow0 = hout + (long)b0 * T_ * 128 + dir * 64 + 16 * w + 4 * q;
  ushort* hRow1 = hout + (long)b1 * T_ * 128 + dir * 64 + 16 * w + 4 * q;

  float cst0[4] = {0.f, 0.f, 0.f, 0.f};
  float cst1[4] = {0.f, 0.f, 0.f, 0.f};
  uint2 huv0 = {0u, 0u}, huv1 = {0u, 0u};

  // 4-deep xg prefetch per group (32B/step/lane each)
  uint4 x0A[4], x0B[4], x1A[4], x1B[4];
#pragma unroll
  for (int j = 0; j < 4; ++j) {
    const int tt = dir ? (T_ - 1 - j) : j;
    x0A[j] = *(const uint4*)(xgb0 + (long)tt * 512);
    x0B[j] = *(const uint4*)(xgb0 + (long)tt * 512 + 16);
    x1A[j] = *(const uint4*)(xgb1 + (long)tt * 512);
    x1B[j] = *(const uint4*)(xgb1 + (long)tt * 512 + 16);
  }
  __syncthreads();

  for (int ph = 0; ph < 128; ++ph) {
    const int t0ph = ph * 4;
    PSTEP(0);
    PSTEP(1);
    PSTEP(2);
    PSTEP(3);
  }
}

// ---------------- Attention pool + LayerNorm + FC (fp16 hio) ---------------
__global__ __launch_bounds__(256) void head_kernel(
    const ushort* __restrict__ hio, const float* __restrict__ attn_w,
    const float* __restrict__ attn_b, const float* __restrict__ ln_g,
    const float* __restrict__ ln_b, const float* __restrict__ fc_w,
    const float* __restrict__ fc_b, float* __restrict__ res) {
  const int b = blockIdx.x;
  const int tid = threadIdx.x;
  __shared__ __align__(16) float aw[128];
  __shared__ float l[T_];
  __shared__ float red[16];
  __shared__ float pp[2][128];
  __shared__ float normed[128];
  if (tid < 128) aw[tid] = attn_w[tid];
  __syncthreads();
  const float ab = attn_b[0];

  for (int t = tid; t < T_; t += 256) {
    const ushort* row = hio + ((long)b * T_ + t) * 128;
    float a = ab;
#pragma unroll
    for (int d = 0; d < 128; d += 8) {
      uint4 v = *(const uint4*)(row + d);
      float2 p0 = __half22float2(*(const __half2*)&v.x);
      float2 p1 = __half22float2(*(const __half2*)&v.y);
      float2 p2 = __half22float2(*(const __half2*)&v.z);
      float2 p3 = __half22float2(*(const __half2*)&v.w);
      a += p0.x * aw[d] + p0.y * aw[d + 1] + p1.x * aw[d + 2] +
           p1.y * aw[d + 3] + p2.x * aw[d + 4] + p2.y * aw[d + 5] +
           p3.x * aw[d + 6] + p3.y * aw[d + 7];
    }
    l[t] = a;
  }
  __syncthreads();

  float v0 = l[tid], v1 = l[tid + 256];
  float m = fmaxf(v0, v1);
#pragma unroll
  for (int off = 32; off >= 1; off >>= 1) m = fmaxf(m, __shfl_xor(m, off));
  if ((tid & 63) == 0) red[tid >> 6] = m;
  __syncthreads();
  m = fmaxf(fmaxf(red[0], red[1]), fmaxf(red[2], red[3]));
  float e0 = __expf(v0 - m), e1 = __expf(v1 - m);
  float ssum = e0 + e1;
#pragma unroll
  for (int off = 32; off >= 1; off >>= 1) ssum += __shfl_xor(ssum, off);
  if ((tid & 63) == 0) red[4 + (tid >> 6)] = ssum;
  __syncthreads();
  float inv = 1.f / (red[4] + red[5] + red[6] + red[7]);
  l[tid] = e0 * inv;
  l[tid + 256] = e1 * inv;
  __syncthreads();

  const int d = tid & 127, half = tid >> 7;
  float p = 0.f;
  for (int t = half * 256; t < half * 256 + 256; ++t)
    p += l[t] * h2f(hio[((long)b * T_ + t) * 128 + d]);
  pp[half][d] = p;
  __syncthreads();

  if (tid < 128) {
    float pv = pp[0][tid] + pp[1][tid];
    float s1 = pv, s2 = pv * pv;
#pragma unroll
    for (int off = 32; off >= 1; off >>= 1) {
      s1 += __shfl_xor(s1, off);
      s2 += __shfl_xor(s2, off);
    }
    if ((tid & 63) == 0) {
      red[8 + (tid >> 6) * 2] = s1;
      red[9 + (tid >> 6) * 2] = s2;
    }
  }
  __syncthreads();
  if (tid < 128) {
    float s1 = red[8] + red[10], s2 = red[9] + red[11];
    float mu = s1 * (1.f / 128.f);
    float var = s2 * (1.f / 128.f) - mu * mu;
    float rinv = rsqrtf(var + 1e-5f);
    float pv = pp[0][tid] + pp[1][tid];
    normed[tid] = (pv - mu) * rinv * ln_g[tid] + ln_b[tid];
  }
  __syncthreads();

  if (tid < 2) {
    float a = fc_b[tid];
    for (int d2 = 0; d2 < 128; ++d2) a += normed[d2] * fc_w[tid * 128 + d2];
    res[b * 2 + tid] = a;
  }
}

extern "C" void kernel_launch(void* const* d_in, const int* in_sizes, int n_in,
                              void* d_out, int out_size, void* d_ws,
                              size_t ws_size, hipStream_t stream) {
  const float* x = (const float*)d_in[0];
  const float* conv_w = (const float*)d_in[1];
  const float* conv_b = (const float*)d_in[2];
  const float* w_ih_f = (const float*)d_in[3];
  const float* w_hh_f = (const float*)d_in[4];
  const float* b_f = (const float*)d_in[5];
  const float* w_ih_b = (const float*)d_in[6];
  const float* w_hh_b = (const float*)d_in[7];
  const float* b_b = (const float*)d_in[8];
  const float* attn_w = (const float*)d_in[9];
  const float* attn_b = (const float*)d_in[10];
  const float* ln_g = (const float*)d_in[11];
  const float* ln_b = (const float*)d_in[12];
  const float* fc_w = (const float*)d_in[13];
  const float* fc_b = (const float*)d_in[14];
  float* res = (float*)d_out;

  // ws layout (~161 MiB):
  char* ws = (char*)d_ws;
  ushort* wbT = (ushort*)ws;                      // 294,912 B
  ushort* wP = (ushort*)(ws + 0x60000);           // 131,072 B (scaled)
  ushort* whhP = (ushort*)(ws + 0x80000);         // 65,536 B (fp16, scaled)
  float* biasP = (float*)(ws + 0x90000);          // 2,048 B (scaled)
  ushort* xgP = (ushort*)(ws + 0x100000);         // 134,217,728 B (fp16)
  ushort* y = (ushort*)(ws + 0x100000 + 134217728);  // 33,554,432 B
  ushort* hout = y;  // aliases y (fp16): y is dead after xg_gemm

  pack_w_kernel<<<576, 256, 0, stream>>>(conv_w, wbT);
  pack_wiP_kernel<<<256, 256, 0, stream>>>(w_ih_f, w_ih_b, wP);
  pack_whhP_kernel<<<128, 256, 0, stream>>>(w_hh_f, w_hh_b, whhP);
  pack_biasP_kernel<<<2, 256, 0, stream>>>(b_f, b_b, biasP);
  conv_gemm_kernel<<<B_ * (T_ / 128), 256, 0, stream>>>(x, wbT, conv_b, y);
  xg_gemm_kernel<<<(B_ * T_ / 128) * 4, 256, 0, stream>>>(y, wP, biasP, xgP);
  lstm_seq_kernel<<<16, 256, 0, stream>>>(whhP, xgP, hout);
  head_kernel<<<B_, 256, 0, stream>>>(hout, attn_w, attn_b, ln_g, ln_b, fc_w,
                                      fc_b, res);
}

// Round 12
// 324.496 us; speedup vs baseline: 2.0408x; 1.8515x over previous
//
#include <hip/hip_runtime.h>
#include <hip/hip_fp16.h>
#include <math.h>

typedef unsigned int uint;
typedef unsigned short ushort;

#define B_ 256
#define T_ 512
#define F_ 378
#define C_ 128
#define H_ 64
#define KPAD 1152   // 3 * 384

using f32x4 = __attribute__((ext_vector_type(4))) float;
using bf16x8 = __attribute__((ext_vector_type(8))) short;
using f16x8 = __attribute__((ext_vector_type(8))) _Float16;

__device__ __forceinline__ ushort f2bf(float f) {
  union { float f; uint u; } c; c.f = f;
  uint r = (c.u + 0x7fffu + ((c.u >> 16) & 1u)) >> 16;
  return (ushort)r;
}
__device__ __forceinline__ uint packbf2(float a, float b) {
  return (uint)f2bf(a) | (((uint)f2bf(b)) << 16);
}
__device__ __forceinline__ ushort f2h(float f) {
  __half h = __float2half(f);
  return *(ushort*)&h;
}
__device__ __forceinline__ float h2f(ushort u) {
  __half h;
  *(ushort*)&h = u;
  return __half2float(h);
}
#define SC_SIG -1.442695041f
#define SC_TANH 2.885390082f

// ---------------- pack conv w -> wbT[c][kk], kk = k*384+f, bf16 ------------
__global__ __launch_bounds__(256) void pack_w_kernel(
    const float* __restrict__ w, ushort* __restrict__ wbT) {
  int i = blockIdx.x * 256 + threadIdx.x;
  if (i >= C_ * KPAD) return;
  int c = i / KPAD, kk = i - c * KPAD;
  int k = kk / 384, f = kk - k * 384;
  float v = (f < F_) ? w[c * (F_ * 3) + f * 3 + k] : 0.f;
  wbT[i] = f2bf(v);
}

// ---- pack w_ih -> wP[dir][g''][128] bf16, PRE-SCALED (4-wave mapping) -----
// g'' = w*64 + q*16 + n*4 + e -> orig gate row e*64 + (16w + 4q + n).
__global__ __launch_bounds__(256) void pack_wiP_kernel(
    const float* __restrict__ wf, const float* __restrict__ wb,
    ushort* __restrict__ wP) {
  int i = blockIdx.x * 256 + threadIdx.x;  // 2*256*128 = 65536
  int dir = i >> 15, rem = i & 32767;
  int gp = rem >> 7, k = rem & 127;
  int e = gp & 3, n = (gp >> 2) & 3, q = (gp >> 4) & 3, w = gp >> 6;
  int u = 16 * w + 4 * q + n;
  const float* src = dir ? wb : wf;
  float scale = (e == 2) ? SC_TANH : SC_SIG;
  wP[i] = f2bf(src[(e * 64 + u) * 128 + k] * scale);
}

// ---- pack w_hh -> whhP[dir][r][64] FP16, PRE-SCALED (4-wave mapping) ------
__global__ __launch_bounds__(256) void pack_whhP_kernel(
    const float* __restrict__ wf, const float* __restrict__ wb,
    ushort* __restrict__ whhP) {
  int i = blockIdx.x * 256 + threadIdx.x;  // 2*256*64 = 32768
  if (i >= 32768) return;
  int dir = i >> 14, rem = i & 16383;
  int r = rem >> 6, k = rem & 63;
  int e = r & 3, q = (r >> 2) & 3, n = (r >> 4) & 3, w = r >> 6;
  int u = 16 * w + 4 * q + n;
  const float* src = dir ? wb : wf;
  float scale = (e == 2) ? SC_TANH : SC_SIG;
  whhP[i] = f2h(src[(e * 64 + u) * 64 + k] * scale);
}

// ---- pack bias -> biasP[dir][g''] fp32, same order+scale as wP ------------
__global__ __launch_bounds__(256) void pack_biasP_kernel(
    const float* __restrict__ bf, const float* __restrict__ bb,
    float* __restrict__ biasP) {
  int i = blockIdx.x * 256 + threadIdx.x;  // 512
  if (i >= 512) return;
  int dir = i >> 8, gp = i & 255;
  int e = gp & 3, n = (gp >> 2) & 3, q = (gp >> 4) & 3, w = gp >> 6;
  int u = 16 * w + 4 * q + n;
  const float* src = dir ? bb : bf;
  float scale = (e == 2) ? SC_TANH : SC_SIG;
  biasP[i] = src[e * 64 + u] * scale;
}

// ---------------- Conv1d as implicit GEMM, bf16 MFMA (unchanged) -----------
__global__ __launch_bounds__(256, 2) void conv_gemm_kernel(
    const float* __restrict__ x, const ushort* __restrict__ wbT,
    const float* __restrict__ bias, ushort* __restrict__ y) {
  __shared__ __align__(16) char xsb[130 * 128];
  __shared__ __align__(16) char bsb[128 * 384];
  const int tid = threadIdx.x;
  const int lane = tid & 63;
  const int wr = (tid >> 7) & 1;
  const int wc = (tid >> 6) & 1;
  const int b = blockIdx.x >> 2;
  const int t0 = (blockIdx.x & 3) << 7;

  f32x4 acc[4][4];
#pragma unroll
  for (int m = 0; m < 4; ++m)
#pragma unroll
    for (int n = 0; n < 4; ++n) acc[m][n] = (f32x4)(0.f);

  for (int fs = 0; fs < 6; ++fs) {
    __syncthreads();
    {
      auto stage_a = [&](int r, int h) {
        const int t = t0 - 1 + r;
        const bool ok = (t >= 0) && (t < T_);
        const float* srow = x + ((long)b * T_ + (ok ? t : 0)) * F_;
        const int fb = fs * 64 + h * 32;
        char* dst = xsb + r * 128;
        const int sw = (r & 7) << 4;
        uint pk[16];
        if (ok && fb + 31 < F_) {
#pragma unroll
          for (int j = 0; j < 16; ++j) {
            float2 v = *(const float2*)(srow + fb + 2 * j);
            pk[j] = packbf2(v.x, v.y);
          }
        } else {
#pragma unroll
          for (int j = 0; j < 16; ++j) {
            const int f = fb + 2 * j;
            float a = (ok && f < F_) ? srow[f] : 0.f;
            float c2 = (ok && f + 1 < F_) ? srow[f + 1] : 0.f;
            pk[j] = packbf2(a, c2);
          }
        }
#pragma unroll
        for (int j = 0; j < 4; ++j) {
          uint4 p = {pk[4 * j], pk[4 * j + 1], pk[4 * j + 2], pk[4 * j + 3]};
          *(uint4*)(dst + ((h * 64 + j * 16) ^ sw)) = p;
        }
      };
      stage_a(tid >> 1, tid & 1);
      if (tid < 4) stage_a(128 + (tid >> 1), tid & 1);
    }
    {
      const int c = tid >> 1, h = tid & 1;
      const ushort* src = wbT + c * KPAD + fs * 64 + h * 32;
      char* drow = bsb + c * 384;
      const int sw = (c & 7) << 4;
#pragma unroll
      for (int k = 0; k < 3; ++k)
#pragma unroll
        for (int j = 0; j < 4; ++j) {
          uint4 v = *(const uint4*)(src + k * 384 + j * 8);
          *(uint4*)(drow + k * 128 + ((h * 64 + j * 16) ^ sw)) = v;
        }
    }
    __syncthreads();

#pragma unroll
    for (int k = 0; k < 3; ++k) {
#pragma unroll
      for (int s = 0; s < 2; ++s) {
        bf16x8 af[4], bfx[4];
        const int ksub = s * 64 + ((lane >> 4) << 4);
#pragma unroll
        for (int m = 0; m < 4; ++m) {
          const int rr = wr * 64 + m * 16 + (lane & 15) + k;
          af[m] = *(const bf16x8*)(xsb + rr * 128 + (ksub ^ ((rr & 7) << 4)));
        }
#pragma unroll
        for (int n = 0; n < 4; ++n) {
          const int c = wc * 64 + n * 16 + (lane & 15);
          bfx[n] =
              *(const bf16x8*)(bsb + c * 384 + k * 128 + (ksub ^ ((c & 7) << 4)));
        }
#pragma unroll
        for (int m = 0; m < 4; ++m)
#pragma unroll
          for (int n = 0; n < 4; ++n)
            acc[m][n] = __builtin_amdgcn_mfma_f32_16x16x32_bf16(
                af[m], bfx[n], acc[m][n], 0, 0, 0);
      }
    }
  }

  __syncthreads();
  float bc[4];
#pragma unroll
  for (int n = 0; n < 4; ++n) bc[n] = bias[wc * 64 + n * 16 + (lane & 15)];
#pragma unroll
  for (int m = 0; m < 4; ++m) {
#pragma unroll
    for (int n = 0; n < 4; ++n) {
      const int col = wc * 64 + n * 16 + (lane & 15);
#pragma unroll
      for (int r = 0; r < 4; ++r) {
        const int row = wr * 64 + m * 16 + ((lane >> 4) << 2) + r;
        float v = acc[m][n][r] + bc[n];
        v = v > 0.f ? v : 0.f;
        *(ushort*)(bsb + row * 256 + ((col * 2) ^ ((row & 7) << 4))) = f2bf(v);
      }
    }
  }
  __syncthreads();
  const int w = tid >> 6;
#pragma unroll
  for (int p = 0; p < 8; ++p) {
    const int rowb = p * 16 + w * 4 + (lane >> 4);
    const int colb = (lane & 15) * 16;
    uint4 v = *(const uint4*)(bsb + rowb * 256 + (colb ^ ((rowb & 7) << 4)));
    *(uint4*)((char*)(y + ((long)b * T_ + t0 + rowb) * 128) + colb) = v;
  }
}

// ---------------- xg GEMM: xgP[dir][b*T+t][256] fp16 = y @ wP^T + bias -----
__global__ __launch_bounds__(256, 2) void xg_gemm_kernel(
    const ushort* __restrict__ y, const ushort* __restrict__ wP,
    const float* __restrict__ biasP, ushort* __restrict__ xgP) {
  __shared__ __align__(16) char xsb[128 * 256];
  __shared__ __align__(16) char bsb[128 * 256];
  const int tid = threadIdx.x;
  const int lane = tid & 63;
  const int wr = (tid >> 7) & 1;
  const int wc = (tid >> 6) & 1;
  const int mb = blockIdx.x >> 2;
  const int nb = blockIdx.x & 3;
  const int m0 = mb << 7;
  const int dirBT = (nb >> 1) * (B_ * T_);
  const int gbase = (nb >> 1) * 256 + (nb & 1) * 128;

  {
    const int r = tid >> 1, h = tid & 1;
    const int sw = (r & 7) << 4;
    const ushort* sa = y + ((long)(m0 + r)) * 128 + h * 64;
    const ushort* sb = wP + (gbase + r) * 128 + h * 64;
    char* da = xsb + r * 256;
    char* db = bsb + r * 256;
#pragma unroll
    for (int j = 0; j < 8; ++j) {
      uint4 va = *(const uint4*)(sa + 8 * j);
      uint4 vb = *(const uint4*)(sb + 8 * j);
      const int inner = (h * 128 + j * 16) ^ sw;
      *(uint4*)(da + inner) = va;
      *(uint4*)(db + inner) = vb;
    }
  }
  __syncthreads();

  f32x4 acc[4][4];
#pragma unroll
  for (int m = 0; m < 4; ++m)
#pragma unroll
    for (int n = 0; n < 4; ++n) acc[m][n] = (f32x4)(0.f);

#pragma unroll
  for (int ks = 0; ks < 4; ++ks) {
    bf16x8 af[4], bfx[4];
    const int ksub = ks * 64 + ((lane >> 4) << 4);
#pragma unroll
    for (int m = 0; m < 4; ++m) {
      const int rr = wr * 64 + m * 16 + (lane & 15);
      af[m] = *(const bf16x8*)(xsb + rr * 256 + (ksub ^ ((rr & 7) << 4)));
    }
#pragma unroll
    for (int n = 0; n < 4; ++n) {
      const int c = wc * 64 + n * 16 + (lane & 15);
      bfx[n] = *(const bf16x8*)(bsb + c * 256 + (ksub ^ ((c & 7) << 4)));
    }
#pragma unroll
    for (int m = 0; m < 4; ++m)
#pragma unroll
      for (int n = 0; n < 4; ++n)
        acc[m][n] = __builtin_amdgcn_mfma_f32_16x16x32_bf16(af[m], bfx[n],
                                                            acc[m][n], 0, 0, 0);
  }

  __syncthreads();
  float bc[4];
#pragma unroll
  for (int n = 0; n < 4; ++n)
    bc[n] = biasP[gbase + wc * 64 + n * 16 + (lane & 15)];
#pragma unroll
  for (int m = 0; m < 4; ++m) {
#pragma unroll
    for (int n = 0; n < 4; ++n) {
      const int col = wc * 64 + n * 16 + (lane & 15);
#pragma unroll
      for (int r = 0; r < 4; ++r) {
        const int row = wr * 64 + m * 16 + ((lane >> 4) << 2) + r;
        float v = acc[m][n][r] + bc[n];
        *(ushort*)(bsb + row * 256 + ((col * 2) ^ ((row & 7) << 4))) = f2h(v);
      }
    }
  }
  __syncthreads();
  const int w = tid >> 6;
#pragma unroll
  for (int p = 0; p < 8; ++p) {
    const int rowb = p * 16 + w * 4 + (lane >> 4);
    const int colb = (lane & 15) * 16;
    uint4 v = *(const uint4*)(bsb + rowb * 256 + (colb ^ ((rowb & 7) << 4)));
    *(uint4*)((char*)xgP + ((long)(dirBT + m0 + rowb)) * 512 + (nb & 1) * 256 +
              colb) = v;
  }
}

// ---------------- LSTM scan: 4 seqs/block, replica-spread nonlinearity -----
// 128 blocks (2 dir x 64 groups), 4 waves. MFMA cols c = 4r+s: 4 seqs x 4
// replicas (B cols duplicated -> identical G in replica lanes). Lane (c,q)
// of wave w holds gates of units 16w+4q+{0..3}; replica r applies the
// nonlinearity ONLY to unit n=r -> 1 unit/lane -> 8 trans-ops per wave-step
// (vs 40 in the 16-seq layout). h exchange via LDS [parity][s][u] fp16 with
// 144B row stride (conflict-free b128 reads). Merged-rcp nonlin (5 exp +
// 3 rcp, pre-scaled weights).
union U2 { uint u; __half2 h2; };

#define LSTEP(J, XR)                                                           \
  do {                                                                         \
    const int t_ = t0ph + (J);                                                 \
    const int p_ = t_ & 1;                                                     \
    const uint2 cur = XR;                                                      \
    {                                                                          \
      int tp = t_ + 4;                                                         \
      tp = tp > T_ - 1 ? T_ - 1 : tp;                                          \
      const int ttp = dir ? (T_ - 1 - tp) : tp;                                \
      XR = *(const uint2*)(xgbase + (long)ttp * 512);                          \
    }                                                                          \
    f16x8 bh0, bh1;                                                            \
    {                                                                          \
      const char* hb = hx + p_ * 576 + s * 144;                                \
      bh0 = *(const f16x8*)(hb + q * 16);                                      \
      bh1 = *(const f16x8*)(hb + 64 + q * 16);                                 \
    }                                                                          \
    f32x4 acc[4];                                                              \
    _Pragma("unroll") for (int n = 0; n < 4; ++n) {                            \
      acc[n] = __builtin_amdgcn_mfma_f32_16x16x32_f16(afA[n], bh0,             \
                                                      (f32x4)(0.f), 0, 0, 0);  \
      acc[n] =                                                                 \
          __builtin_amdgcn_mfma_f32_16x16x32_f16(afB[n], bh1, acc[n], 0, 0, 0);\
    }                                                                          \
    float ge[4];                                                               \
    _Pragma("unroll") for (int e = 0; e < 4; ++e) {                            \
      float v01 = (r & 1) ? acc[1][e] : acc[0][e];                             \
      float v23 = (r & 1) ? acc[3][e] : acc[2][e];                             \
      ge[e] = (r & 2) ? v23 : v01;                                             \
    }                                                                          \
    U2 ua, ub;                                                                 \
    ua.u = cur.x;                                                              \
    ub.u = cur.y;                                                              \
    float2 xif = __half22float2(ua.h2);                                        \
    float2 xgo = __half22float2(ub.h2);                                        \
    float gi = ge[0] + xif.x, gf = ge[1] + xif.y;                              \
    float gg = ge[2] + xgo.x, go = ge[3] + xgo.y;                              \
    float Ei = __builtin_amdgcn_exp2f(gi);                                     \
    float Ef = __builtin_amdgcn_exp2f(gf);                                     \
    float Eg = __builtin_amdgcn_exp2f(gg);                                     \
    float Eo = __builtin_amdgcn_exp2f(go);                                     \
    float sf = __builtin_amdgcn_rcpf(1.f + Ef);                                \
    float den = __builtin_amdgcn_rcpf((1.f + Ei) * (1.f + Eg));                \
    cst = fmaf(sf, cst, (Eg - 1.f) * den);                                     \
    float Ec = __builtin_amdgcn_exp2f(SC_TANH * cst);                          \
    float hval = (Ec - 1.f) * __builtin_amdgcn_rcpf((1.f + Eo) * (1.f + Ec));  \
    const ushort hu = f2h(hval);                                               \
    *(ushort*)(hx + (1 - p_) * 576 + s * 144 + ub_) = hu;                      \
    {                                                                          \
      const int gt = dir ? (T_ - 1 - t_) : t_;                                 \
      houtp[(long)gt * 128] = hu;                                              \
    }                                                                          \
    asm volatile("s_waitcnt lgkmcnt(0)" ::: "memory");                         \
    __builtin_amdgcn_sched_barrier(0);                                         \
    __builtin_amdgcn_s_barrier();                                              \
    __builtin_amdgcn_sched_barrier(0);                                         \
  } while (0)

__global__ __launch_bounds__(256, 1) void lstm_seq_kernel(
    const ushort* __restrict__ whhP, const ushort* __restrict__ xgP,
    ushort* __restrict__ hout) {
  const int dir = blockIdx.x >> 6;
  const int bg = blockIdx.x & 63;
  const int tid = threadIdx.x;
  const int lane = tid & 63;
  const int w = tid >> 6;          // wave 0..3
  const int c = lane & 15;         // MFMA column
  const int q = lane >> 4;         // quarter
  const int s = c & 3;             // sequence within group (4 seqs)
  const int r = c >> 2;            // replica id = which unit this lane owns

  // h exchange: [parity][4 s][64 u] fp16, 144B row stride (conflict-free)
  __shared__ __align__(16) char hx[2 * 576];
  for (int i = tid; i < 288; i += 256) ((uint*)hx)[i] = 0u;

  // pinned A-frags (fp16): whhP rows 64w+16n+c, k chunks [0,32),[32,64)
  f16x8 afA[4], afB[4];
  {
    const ushort* base = whhP + (long)dir * 256 * 64;
#pragma unroll
    for (int n = 0; n < 4; ++n) {
      const ushort* rp = base + (64 * w + 16 * n + c) * 64 + q * 8;
      afA[n] = *(const f16x8*)rp;
      afB[n] = *(const f16x8*)(rp + 32);
    }
  }

  const int b = bg * 4 + s;
  const int u = 16 * w + 4 * q + r;  // this lane's unit
  const int ub_ = u * 2;             // byte offset within h row
  const char* xgbase = (const char*)xgP + (((long)dir * B_ + b) * T_) * 512 +
                       w * 128 + q * 32 + r * 8;
  ushort* houtp = hout + (long)b * T_ * 128 + dir * 64 + u;

  float cst = 0.f;

  // 4-deep xg prefetch (8B/step/lane)
  uint2 x0, x1, x2, x3;
  {
    x0 = *(const uint2*)(xgbase + (long)(dir ? T_ - 1 : 0) * 512);
    x1 = *(const uint2*)(xgbase + (long)(dir ? T_ - 2 : 1) * 512);
    x2 = *(const uint2*)(xgbase + (long)(dir ? T_ - 3 : 2) * 512);
    x3 = *(const uint2*)(xgbase + (long)(dir ? T_ - 4 : 3) * 512);
  }
  __syncthreads();

  for (int ph = 0; ph < 128; ++ph) {
    const int t0ph = ph * 4;
    LSTEP(0, x0);
    LSTEP(1, x1);
    LSTEP(2, x2);
    LSTEP(3, x3);
  }
}

// ---------------- Attention pool + LayerNorm + FC (fp16 hio) ---------------
__global__ __launch_bounds__(256) void head_kernel(
    const ushort* __restrict__ hio, const float* __restrict__ attn_w,
    const float* __restrict__ attn_b, const float* __restrict__ ln_g,
    const float* __restrict__ ln_b, const float* __restrict__ fc_w,
    const float* __restrict__ fc_b, float* __restrict__ res) {
  const int b = blockIdx.x;
  const int tid = threadIdx.x;
  __shared__ __align__(16) float aw[128];
  __shared__ float l[T_];
  __shared__ float red[16];
  __shared__ float pp[2][128];
  __shared__ float normed[128];
  if (tid < 128) aw[tid] = attn_w[tid];
  __syncthreads();
  const float ab = attn_b[0];

  for (int t = tid; t < T_; t += 256) {
    const ushort* row = hio + ((long)b * T_ + t) * 128;
    float a = ab;
#pragma unroll
    for (int d = 0; d < 128; d += 8) {
      uint4 v = *(const uint4*)(row + d);
      float2 p0 = __half22float2(*(const __half2*)&v.x);
      float2 p1 = __half22float2(*(const __half2*)&v.y);
      float2 p2 = __half22float2(*(const __half2*)&v.z);
      float2 p3 = __half22float2(*(const __half2*)&v.w);
      a += p0.x * aw[d] + p0.y * aw[d + 1] + p1.x * aw[d + 2] +
           p1.y * aw[d + 3] + p2.x * aw[d + 4] + p2.y * aw[d + 5] +
           p3.x * aw[d + 6] + p3.y * aw[d + 7];
    }
    l[t] = a;
  }
  __syncthreads();

  float v0 = l[tid], v1 = l[tid + 256];
  float m = fmaxf(v0, v1);
#pragma unroll
  for (int off = 32; off >= 1; off >>= 1) m = fmaxf(m, __shfl_xor(m, off));
  if ((tid & 63) == 0) red[tid >> 6] = m;
  __syncthreads();
  m = fmaxf(fmaxf(red[0], red[1]), fmaxf(red[2], red[3]));
  float e0 = __expf(v0 - m), e1 = __expf(v1 - m);
  float ssum = e0 + e1;
#pragma unroll
  for (int off = 32; off >= 1; off >>= 1) ssum += __shfl_xor(ssum, off);
  if ((tid & 63) == 0) red[4 + (tid >> 6)] = ssum;
  __syncthreads();
  float inv = 1.f / (red[4] + red[5] + red[6] + red[7]);
  l[tid] = e0 * inv;
  l[tid + 256] = e1 * inv;
  __syncthreads();

  const int d = tid & 127, half = tid >> 7;
  float p = 0.f;
  for (int t = half * 256; t < half * 256 + 256; ++t)
    p += l[t] * h2f(hio[((long)b * T_ + t) * 128 + d]);
  pp[half][d] = p;
  __syncthreads();

  if (tid < 128) {
    float pv = pp[0][tid] + pp[1][tid];
    float s1 = pv, s2 = pv * pv;
#pragma unroll
    for (int off = 32; off >= 1; off >>= 1) {
      s1 += __shfl_xor(s1, off);
      s2 += __shfl_xor(s2, off);
    }
    if ((tid & 63) == 0) {
      red[8 + (tid >> 6) * 2] = s1;
      red[9 + (tid >> 6) * 2] = s2;
    }
  }
  __syncthreads();
  if (tid < 128) {
    float s1 = red[8] + red[10], s2 = red[9] + red[11];
    float mu = s1 * (1.f / 128.f);
    float var = s2 * (1.f / 128.f) - mu * mu;
    float rinv = rsqrtf(var + 1e-5f);
    float pv = pp[0][tid] + pp[1][tid];
    normed[tid] = (pv - mu) * rinv * ln_g[tid] + ln_b[tid];
  }
  __syncthreads();

  if (tid < 2) {
    float a = fc_b[tid];
    for (int d2 = 0; d2 < 128; ++d2) a += normed[d2] * fc_w[tid * 128 + d2];
    res[b * 2 + tid] = a;
  }
}

extern "C" void kernel_launch(void* const* d_in, const int* in_sizes, int n_in,
                              void* d_out, int out_size, void* d_ws,
                              size_t ws_size, hipStream_t stream) {
  const float* x = (const float*)d_in[0];
  const float* conv_w = (const float*)d_in[1];
  const float* conv_b = (const float*)d_in[2];
  const float* w_ih_f = (const float*)d_in[3];
  const float* w_hh_f = (const float*)d_in[4];
  const float* b_f = (const float*)d_in[5];
  const float* w_ih_b = (const float*)d_in[6];
  const float* w_hh_b = (const float*)d_in[7];
  const float* b_b = (const float*)d_in[8];
  const float* attn_w = (const float*)d_in[9];
  const float* attn_b = (const float*)d_in[10];
  const float* ln_g = (const float*)d_in[11];
  const float* ln_b = (const float*)d_in[12];
  const float* fc_w = (const float*)d_in[13];
  const float* fc_b = (const float*)d_in[14];
  float* res = (float*)d_out;

  // ws layout (~161 MiB):
  char* ws = (char*)d_ws;
  ushort* wbT = (ushort*)ws;                      // 294,912 B
  ushort* wP = (ushort*)(ws + 0x60000);           // 131,072 B (scaled)
  ushort* whhP = (ushort*)(ws + 0x80000);         // 65,536 B (fp16, scaled)
  float* biasP = (float*)(ws + 0x90000);          // 2,048 B (scaled)
  ushort* xgP = (ushort*)(ws + 0x100000);         // 134,217,728 B (fp16)
  ushort* y = (ushort*)(ws + 0x100000 + 134217728);  // 33,554,432 B
  ushort* hout = y;  // aliases y (fp16): y is dead after xg_gemm

  pack_w_kernel<<<576, 256, 0, stream>>>(conv_w, wbT);
  pack_wiP_kernel<<<256, 256, 0, stream>>>(w_ih_f, w_ih_b, wP);
  pack_whhP_kernel<<<128, 256, 0, stream>>>(w_hh_f, w_hh_b, whhP);
  pack_biasP_kernel<<<2, 256, 0, stream>>>(b_f, b_b, biasP);
  conv_gemm_kernel<<<B_ * (T_ / 128), 256, 0, stream>>>(x, wbT, conv_b, y);
  xg_gemm_kernel<<<(B_ * T_ / 128) * 4, 256, 0, stream>>>(y, wP, biasP, xgP);
  lstm_seq_kernel<<<128, 256, 0, stream>>>(whhP, xgP, hout);
  head_kernel<<<B_, 256, 0, stream>>>(hout, attn_w, attn_b, ln_g, ln_b, fc_w,
                                      fc_b, res);
}